// Round 1
// baseline (608.202 us; speedup 1.0000x reference)
//
#include <hip/hip_runtime.h>

// Problem constants
#define CK 64
#define CKP 128          // packed K (mk ; mk^2)
#define OCV 1024         // O*CV
#define NTOT 25920       // T*H*W
#define HW 1620
#define HWP 1664         // padded to 13*128
#define QT 128           // q tile
#define VT 256           // v tile
#define NC 64            // n chunk
#define NQT 13
#define NVT 4
#define NSPLIT 2
#define CHUNKS_TOTAL 405
#define CHUNK_SPLIT 203

typedef _Float16 f16x8 __attribute__((ext_vector_type(8)));
typedef _Float16 f16x4 __attribute__((ext_vector_type(4)));
typedef float f32x4 __attribute__((ext_vector_type(4)));

// ---- prep: memory_value fp32 -> fp16 (pure streaming convert, layout identical)
__global__ void k_prep_mv(const float* __restrict__ mv, _Float16* __restrict__ mvh) {
  int i = blockIdx.x * 256 + threadIdx.x;          // 6,635,520 threads, 8 elems each
  const float4* s = (const float4*)mv + (size_t)i * 2;
  float4 a = s[0], b = s[1];
  f16x8 o;
  o[0]=(_Float16)a.x; o[1]=(_Float16)a.y; o[2]=(_Float16)a.z; o[3]=(_Float16)a.w;
  o[4]=(_Float16)b.x; o[5]=(_Float16)b.y; o[6]=(_Float16)b.z; o[7]=(_Float16)b.w;
  *((f16x8*)mvh + i) = o;
}

// ---- prep: memory_key -> MKpack[b][n][k] fp16, k in [0,128): rows mk then mk^2
__global__ void k_prep_mk(const float* __restrict__ mk, _Float16* __restrict__ mkp) {
  __shared__ _Float16 LT[64 * CKP];
  int b = blockIdx.y, n0 = blockIdx.x * 64;
  int c4 = threadIdx.x >> 6, nl = threadIdx.x & 63;
  for (int c = c4; c < 64; c += 4) {
    float v = mk[((size_t)(b * 64 + c)) * NTOT + n0 + nl];
    LT[nl * CKP + c]      = (_Float16)v;
    LT[nl * CKP + 64 + c] = (_Float16)(v * v);
  }
  __syncthreads();
  #pragma unroll
  for (int k = 0; k < 4; ++k) {
    int idx = threadIdx.x + 256 * k;
    int n = idx >> 4, c16 = idx & 15;
    *((uint4*)(mkp + ((size_t)b * NTOT + n0 + n) * CKP + c16 * 8)) =
        *((const uint4*)(&LT[n * CKP + c16 * 8]));
  }
}

// ---- prep: Qpack[b][q][k] fp16 (rows 2*qk*qe then -qe), bsq[b][q] fp32; pad q>=1620 with 0
__global__ void k_prep_q(const float* __restrict__ qk, const float* __restrict__ qe,
                         _Float16* __restrict__ qp, float* __restrict__ bsq) {
  __shared__ _Float16 LT[QT * CKP];
  int b = blockIdx.y, q0 = blockIdx.x * QT;
  int t = threadIdx.x;
  int q = q0 + t;
  bool valid = q < HW;
  float acc = 0.f;
  for (int c = 0; c < 64; ++c) {
    float a = valid ? qk[((size_t)(b * 64 + c)) * HW + q] : 0.f;
    float e = valid ? qe[((size_t)(b * 64 + c)) * HW + q] : 0.f;
    LT[t * CKP + c]      = (_Float16)(2.f * a * e);
    LT[t * CKP + 64 + c] = (_Float16)(-e);
    acc += e * a * a;
  }
  bsq[(size_t)b * HWP + q] = acc;   // 0 for pad columns
  __syncthreads();
  #pragma unroll
  for (int k = 0; k < 16; ++k) {
    int idx = t + 128 * k;
    int qq = idx >> 4, c16 = idx & 15;
    *((uint4*)(qp + ((size_t)b * HWP + q0 + qq) * CKP + c16 * 8)) =
        *((const uint4*)(&LT[qq * CKP + c16 * 8]));
  }
}

// ---- fused main: per block (qt, vt, b, nsplit): loop n-chunks:
//      S = MK x Q (K=128 MFMA) -> p = exp((S-bsq)*ms/8) -> P fp16 in LDS -> O' += MV x P
__launch_bounds__(512, 1)
__global__ void k_main(const _Float16* __restrict__ mvh, const _Float16* __restrict__ mkp,
                       const _Float16* __restrict__ qp, const float* __restrict__ bsq,
                       const float* __restrict__ ms,
                       float* __restrict__ pO, float* __restrict__ lpart) {
  const int qt = blockIdx.x, vt = blockIdx.y;
  const int b = blockIdx.z >> 1, nsp = blockIdx.z & 1;
  const int tid = threadIdx.x;
  const int w = tid >> 6, l = tid & 63;
  const int l15 = l & 15, g = l >> 4;

  __shared__ _Float16 Qs[QT * CKP];   // 32KB [q][slot*8+i], slot = kb ^ (q&7)
  __shared__ _Float16 MKs[NC * CKP];  // 16KB [n][slot*8+i], slot = kb ^ (n&7)
  __shared__ _Float16 MVs[VT * NC];   // 32KB [v][slot*8+i], slot = j8 ^ (v&7)
  __shared__ _Float16 Ps[QT * NC];    // 16KB [q][slot*8+i], slot = nb ^ (q&7)
  __shared__ float msc[NC];
  __shared__ float bsqs[QT];
  __shared__ float lred[QT * 8];

  // stage Q tile once (swizzled) + bsq
  #pragma unroll
  for (int k = 0; k < 4; ++k) {
    int s = tid + k * 512;
    int q = s >> 4, kb = s & 15;
    uint4 v = *((const uint4*)(qp + ((size_t)b * HWP + qt * QT + q) * CKP + kb * 8));
    *((uint4*)(&Qs[q * CKP + ((kb ^ (q & 7)) * 8)])) = v;
  }
  if (tid < QT) bsqs[tid] = bsq[(size_t)b * HWP + qt * QT + tid];

  f32x4 acc[4][4];
  #pragma unroll
  for (int i = 0; i < 4; ++i)
    #pragma unroll
    for (int j = 0; j < 4; ++j) acc[i][j] = (f32x4)0.f;
  float lp0 = 0.f, lp1 = 0.f;

  const int qw = w & 3, nh = w >> 2;   // S-phase wave roles: q in [qw*32,+32), n in [nh*32,+32)
  const int wv = w & 3, wq = w >> 2;   // readout roles: v in [wv*64,+64), q in [wq*64,+64)

  const int cBeg = nsp ? CHUNK_SPLIT : 0;
  const int cEnd = nsp ? CHUNKS_TOTAL : CHUNK_SPLIT;

  for (int ch = cBeg; ch < cEnd; ++ch) {
    const int n0 = ch * NC;
    __syncthreads();                    // prior readout done; safe to overwrite tiles
    // stage MV chunk (fp16, swizzled)
    #pragma unroll
    for (int k = 0; k < 4; ++k) {
      int s = tid + k * 512;
      int v = s >> 3, j8 = s & 7;
      uint4 d = *((const uint4*)(mvh + ((size_t)b * OCV + vt * VT + v) * NTOT + n0 + j8 * 8));
      *((uint4*)(&MVs[v * NC + ((j8 ^ (v & 7)) * 8)])) = d;
    }
    // stage MK chunk
    #pragma unroll
    for (int k = 0; k < 2; ++k) {
      int s = tid + k * 512;
      int n = s >> 4, kb = s & 15;
      uint4 d = *((const uint4*)(mkp + ((size_t)b * NTOT + n0 + n) * CKP + kb * 8));
      *((uint4*)(&MKs[n * CKP + ((kb ^ (n & 7)) * 8)])) = d;
    }
    if (tid < NC) msc[tid] = ms[(size_t)b * NTOT + n0 + tid] * (0.125f * 1.44269504f);
    __syncthreads();

    // ---- S GEMM: 64n x 128q, K=128
    f32x4 sacc[2][2];
    #pragma unroll
    for (int i = 0; i < 2; ++i)
      #pragma unroll
      for (int j = 0; j < 2; ++j) sacc[i][j] = (f32x4)0.f;
    #pragma unroll
    for (int ks = 0; ks < 4; ++ks) {
      f16x8 af[2], bf[2];
      #pragma unroll
      for (int i = 0; i < 2; ++i) {
        int n_loc = nh * 32 + i * 16 + l15;
        af[i] = *((const f16x8*)(&MKs[n_loc * CKP + (((ks * 4 + g) ^ (n_loc & 7)) * 8)]));
      }
      #pragma unroll
      for (int j = 0; j < 2; ++j) {
        int q_loc = qw * 32 + j * 16 + l15;
        bf[j] = *((const f16x8*)(&Qs[q_loc * CKP + (((ks * 4 + g) ^ (q_loc & 7)) * 8)]));
      }
      #pragma unroll
      for (int i = 0; i < 2; ++i)
        #pragma unroll
        for (int j = 0; j < 2; ++j)
          sacc[i][j] = __builtin_amdgcn_mfma_f32_16x16x32_f16(af[i], bf[j], sacc[i][j], 0, 0, 0);
    }
    // p = exp(S); write P fp16 (swizzled); accumulate per-lane l partials
    #pragma unroll
    for (int i = 0; i < 2; ++i) {
      int nbase = nh * 32 + i * 16 + g * 4;     // D-frag rows: (l>>4)*4 + r
      float m0 = msc[nbase], m1 = msc[nbase + 1], m2 = msc[nbase + 2], m3 = msc[nbase + 3];
      #pragma unroll
      for (int j = 0; j < 2; ++j) {
        int q_loc = qw * 32 + j * 16 + l15;     // D-frag col: l&15
        float bqv = bsqs[q_loc];
        float p0 = exp2f((sacc[i][j][0] - bqv) * m0);
        float p1 = exp2f((sacc[i][j][1] - bqv) * m1);
        float p2 = exp2f((sacc[i][j][2] - bqv) * m2);
        float p3 = exp2f((sacc[i][j][3] - bqv) * m3);
        float psum = (p0 + p1) + (p2 + p3);
        if (j == 0) lp0 += psum; else lp1 += psum;
        f16x4 ph;
        ph[0]=(_Float16)p0; ph[1]=(_Float16)p1; ph[2]=(_Float16)p2; ph[3]=(_Float16)p3;
        int nb = nbase >> 3;
        int off4 = nbase & 7;                    // 0 or 4
        *((f16x4*)(&Ps[q_loc * NC + ((nb ^ (q_loc & 7)) * 8) + off4])) = ph;
      }
    }
    __syncthreads();

    // ---- readout GEMM: 256v x 128q, K = 64
    #pragma unroll
    for (int ks = 0; ks < 2; ++ks) {
      f16x8 av[4], bp[4];
      #pragma unroll
      for (int i = 0; i < 4; ++i) {
        int v_loc = wv * 64 + i * 16 + l15;
        av[i] = *((const f16x8*)(&MVs[v_loc * NC + (((ks * 4 + g) ^ (v_loc & 7)) * 8)]));
      }
      #pragma unroll
      for (int j = 0; j < 4; ++j) {
        int q_loc = wq * 64 + j * 16 + l15;
        bp[j] = *((const f16x8*)(&Ps[q_loc * NC + (((ks * 4 + g) ^ (q_loc & 7)) * 8)]));
      }
      #pragma unroll
      for (int i = 0; i < 4; ++i)
        #pragma unroll
        for (int j = 0; j < 4; ++j)
          acc[i][j] = __builtin_amdgcn_mfma_f32_16x16x32_f16(av[i], bp[j], acc[i][j], 0, 0, 0);
    }
  }

  // epilogue: reduce per-lane l partials (8 contributors per q)
  {
    int q0a = qw * 32 + l15;
    lred[q0a * 8 + nh * 4 + g] = lp0;
    lred[(q0a + 16) * 8 + nh * 4 + g] = lp1;
  }
  __syncthreads();
  if (tid < QT) {
    float s = 0.f;
    #pragma unroll
    for (int j = 0; j < 8; ++j) s += lred[tid * 8 + j];
    lpart[((size_t)b * NSPLIT + nsp) * HWP + qt * QT + tid] = s;  // identical across vt blocks
  }
  // store unnormalized partial O'
  #pragma unroll
  for (int i = 0; i < 4; ++i) {
    #pragma unroll
    for (int j = 0; j < 4; ++j) {
      #pragma unroll
      for (int r = 0; r < 4; ++r) {
        int v_glob = vt * VT + wv * 64 + i * 16 + g * 4 + r;
        int q_l = qt * QT + wq * 64 + j * 16 + l15;
        pO[(((size_t)b * NSPLIT + nsp) * OCV + v_glob) * HWP + q_l] = acc[i][j][r];
      }
    }
  }
}

// ---- final: out = (O'0 + O'1) / (l0 + l1)
__global__ void k_reduce(const float* __restrict__ pO, const float* __restrict__ lpart,
                         float* __restrict__ out) {
  int i = blockIdx.x * 256 + threadIdx.x;   // 829,440 = 2*1024*405
  int q4 = i % 405;
  int rest = i / 405;
  int v = rest & (OCV - 1);
  int b = rest >> 10;
  int q = q4 * 4;
  const float4 p0 = *((const float4*)(pO + (((size_t)b * NSPLIT + 0) * OCV + v) * HWP + q));
  const float4 p1 = *((const float4*)(pO + (((size_t)b * NSPLIT + 1) * OCV + v) * HWP + q));
  const float4 l0 = *((const float4*)(lpart + ((size_t)b * NSPLIT + 0) * HWP + q));
  const float4 l1 = *((const float4*)(lpart + ((size_t)b * NSPLIT + 1) * HWP + q));
  float4 o;
  o.x = (p0.x + p1.x) / (l0.x + l1.x);
  o.y = (p0.y + p1.y) / (l0.y + l1.y);
  o.z = (p0.z + p1.z) / (l0.z + l1.z);
  o.w = (p0.w + p1.w) / (l0.w + l1.w);
  *((float4*)(out + ((size_t)b * OCV + v) * HW + q)) = o;
}

extern "C" void kernel_launch(void* const* d_in, const int* in_sizes, int n_in,
                              void* d_out, int out_size, void* d_ws, size_t ws_size,
                              hipStream_t stream) {
  const float* qk = (const float*)d_in[0];
  const float* qe = (const float*)d_in[1];
  const float* mk = (const float*)d_in[2];
  const float* ms = (const float*)d_in[3];
  const float* mv = (const float*)d_in[4];
  float* out = (float*)d_out;

  char* p = (char*)d_ws;
  _Float16* mvh = (_Float16*)p; p += (size_t)2 * OCV * NTOT * 2;     // 106.2 MB
  _Float16* mkp = (_Float16*)p; p += (size_t)2 * NTOT * CKP * 2;     // 13.3 MB
  _Float16* qp  = (_Float16*)p; p += (size_t)2 * HWP * CKP * 2;      // 0.85 MB
  float* bsqw   = (float*)p;    p += (size_t)2 * HWP * 4;
  float* lpart  = (float*)p;    p += (size_t)2 * NSPLIT * HWP * 4;
  float* pO     = (float*)p;    p += (size_t)2 * NSPLIT * OCV * HWP * 4;  // 27.3 MB
  size_t need = (size_t)(p - (char*)d_ws);
  if (ws_size < need) return;   // diagnostic: absmax ~= max|ref| and zero dispatches => ws too small

  k_prep_mv<<<25920, 256, 0, stream>>>(mv, mvh);
  k_prep_mk<<<dim3(405, 2), 256, 0, stream>>>(mk, mkp);
  k_prep_q<<<dim3(NQT, 2), QT, 0, stream>>>(qk, qe, qp, bsqw);
  k_main<<<dim3(NQT, NVT, 4), 512, 0, stream>>>(mvh, mkp, qp, bsqw, ms, pO, lpart);
  k_reduce<<<3240, 256, 0, stream>>>(pO, lpart, out);
}

// Round 2
// 552.319 us; speedup vs baseline: 1.1012x; 1.1012x over previous
//
#include <hip/hip_runtime.h>
#include <stdint.h>

// Problem constants
#define CK 64
#define CKP 128          // packed K (mk ; mk^2)
#define OCV 1024         // O*CV
#define NTOT 25920       // T*H*W
#define HW 1620
#define HWP 1664         // padded to 13*128
#define QT 128           // q tile
#define VT 256           // v tile
#define NC 64            // n chunk
#define NQT 13
#define NVT 4
#define NSPLIT 2
#define CHUNKS_TOTAL 405
#define CHUNK_SPLIT 203

typedef _Float16 f16x8 __attribute__((ext_vector_type(8)));
typedef _Float16 f16x4 __attribute__((ext_vector_type(4)));
typedef float f32x4 __attribute__((ext_vector_type(4)));

__device__ __forceinline__ void gload_lds16(const void* g, void* l) {
  __builtin_amdgcn_global_load_lds(
      (const __attribute__((address_space(1))) uint32_t*)g,
      (__attribute__((address_space(3))) uint32_t*)l, 16, 0, 0);
}

// ---- prep: memory_value fp32 -> fp16 (pure streaming convert, layout identical)
__global__ void k_prep_mv(const float* __restrict__ mv, _Float16* __restrict__ mvh) {
  int i = blockIdx.x * 256 + threadIdx.x;
  const float4* s = (const float4*)mv + (size_t)i * 2;
  float4 a = s[0], b = s[1];
  f16x8 o;
  o[0]=(_Float16)a.x; o[1]=(_Float16)a.y; o[2]=(_Float16)a.z; o[3]=(_Float16)a.w;
  o[4]=(_Float16)b.x; o[5]=(_Float16)b.y; o[6]=(_Float16)b.z; o[7]=(_Float16)b.w;
  *((f16x8*)mvh + i) = o;
}

// ---- prep: memory_key -> MKpack[b][n][k] fp16, k in [0,128): rows mk then mk^2
__global__ void k_prep_mk(const float* __restrict__ mk, _Float16* __restrict__ mkp) {
  __shared__ _Float16 LT[64 * CKP];
  int b = blockIdx.y, n0 = blockIdx.x * 64;
  int c4 = threadIdx.x >> 6, nl = threadIdx.x & 63;
  for (int c = c4; c < 64; c += 4) {
    float v = mk[((size_t)(b * 64 + c)) * NTOT + n0 + nl];
    LT[nl * CKP + c]      = (_Float16)v;
    LT[nl * CKP + 64 + c] = (_Float16)(v * v);
  }
  __syncthreads();
  #pragma unroll
  for (int k = 0; k < 4; ++k) {
    int idx = threadIdx.x + 256 * k;
    int n = idx >> 4, c16 = idx & 15;
    *((uint4*)(mkp + ((size_t)b * NTOT + n0 + n) * CKP + c16 * 8)) =
        *((const uint4*)(&LT[n * CKP + c16 * 8]));
  }
}

// ---- prep: Qpack[b][q][k] fp16 (rows 2*qk*qe then -qe), bsq[b][q] fp32; pad q>=1620 with 0
__global__ void k_prep_q(const float* __restrict__ qk, const float* __restrict__ qe,
                         _Float16* __restrict__ qp, float* __restrict__ bsq) {
  __shared__ _Float16 LT[QT * CKP];
  int b = blockIdx.y, q0 = blockIdx.x * QT;
  int t = threadIdx.x;
  int q = q0 + t;
  bool valid = q < HW;
  float acc = 0.f;
  for (int c = 0; c < 64; ++c) {
    float a = valid ? qk[((size_t)(b * 64 + c)) * HW + q] : 0.f;
    float e = valid ? qe[((size_t)(b * 64 + c)) * HW + q] : 0.f;
    LT[t * CKP + c]      = (_Float16)(2.f * a * e);
    LT[t * CKP + 64 + c] = (_Float16)(-e);
    acc += e * a * a;
  }
  bsq[(size_t)b * HWP + q] = acc;
  __syncthreads();
  #pragma unroll
  for (int k = 0; k < 16; ++k) {
    int idx = t + 128 * k;
    int qq = idx >> 4, c16 = idx & 15;
    *((uint4*)(qp + ((size_t)b * HWP + q0 + qq) * CKP + c16 * 8)) =
        *((const uint4*)(&LT[qq * CKP + c16 * 8]));
  }
}

// ---- fused main, double-buffered async staging:
//  per chunk: {issue ch+1 gload_lds} -> S=MK x Q -> exp -> Ps -> [lgkm barrier]
//             -> readout O' += MV x P -> [vmcnt(0) barrier] -> flip
__launch_bounds__(512, 1)
__global__ void k_main(const _Float16* __restrict__ mvh, const _Float16* __restrict__ mkp,
                       const _Float16* __restrict__ qp, const float* __restrict__ bsq,
                       const float* __restrict__ ms,
                       float* __restrict__ pO, float* __restrict__ lpart) {
  const int qt = blockIdx.x, vt = blockIdx.y;
  const int b = blockIdx.z >> 1, nsp = blockIdx.z & 1;
  const int tid = threadIdx.x;
  const int w = tid >> 6, l = tid & 63;
  const int l15 = l & 15, g = l >> 4;

  __shared__ _Float16 Qs[QT * CKP];       // 32KB, [q][slot^ (q&7)]
  __shared__ _Float16 MKs[2][NC * CKP];   // 2x16KB, linear dest, source pre-swizzled
  __shared__ _Float16 MVs[2][VT * NC];    // 2x32KB, linear dest, source pre-swizzled
  __shared__ _Float16 Ps[QT * NC];        // 16KB
  __shared__ float bsqs[QT];
  __shared__ float lred[QT * 8];

  const int qw = w & 3, nh = w >> 2;      // S-phase wave roles
  const int wv = w & 3, wq = w >> 2;      // readout roles

  const int cBeg = nsp ? CHUNK_SPLIT : 0;
  const int cEnd = nsp ? CHUNKS_TOTAL : CHUNK_SPLIT;

  // per-thread async-staging source bases (chunk n=0) + linear LDS byte offsets.
  // LDS[v][s] must hold global slot j = s ^ (v&7)  (inverse-swizzle on source).
  const char* mvb[4]; int dmv[4];
  #pragma unroll
  for (int k = 0; k < 4; ++k) {
    int idx = k * 512 + tid;
    int v = idx >> 3, s = idx & 7, j = s ^ (v & 7);
    mvb[k] = (const char*)(mvh + ((size_t)b * OCV + vt * VT + v) * NTOT + j * 8);
    dmv[k] = idx * 16;
  }
  const char* mkb[2]; int dmk[2];
  #pragma unroll
  for (int k = 0; k < 2; ++k) {
    int idx = k * 512 + tid;
    int n = idx >> 4, s = idx & 15, j = s ^ (n & 7);
    mkb[k] = (const char*)(mkp + ((size_t)b * NTOT + n) * CKP + j * 8);
    dmk[k] = idx * 16;
  }
  const float* msb = ms + (size_t)b * NTOT + nh * 32 + g * 4;

  // prologue: async-stage chunk cBeg into buf0; stage Q tile + bsq
  {
    size_t omv = (size_t)cBeg * (NC * 2);
    size_t omk = (size_t)cBeg * (NC * CKP * 2);
    #pragma unroll
    for (int k = 0; k < 4; ++k) gload_lds16(mvb[k] + omv, (char*)MVs[0] + dmv[k]);
    #pragma unroll
    for (int k = 0; k < 2; ++k) gload_lds16(mkb[k] + omk, (char*)MKs[0] + dmk[k]);
  }
  #pragma unroll
  for (int k = 0; k < 4; ++k) {
    int s = tid + k * 512;
    int q = s >> 4, kb = s & 15;
    uint4 v = *((const uint4*)(qp + ((size_t)b * HWP + qt * QT + q) * CKP + kb * 8));
    *((uint4*)(&Qs[q * CKP + ((kb ^ (q & 7)) * 8)])) = v;
  }
  if (tid < QT) bsqs[tid] = bsq[(size_t)b * HWP + qt * QT + tid];
  __syncthreads();   // drains vmcnt(0)+lgkmcnt(0): chunk0 + Qs ready

  f32x4 acc[4][4];
  #pragma unroll
  for (int i = 0; i < 4; ++i)
    #pragma unroll
    for (int j = 0; j < 4; ++j) acc[i][j] = (f32x4)0.f;
  float lp0 = 0.f, lp1 = 0.f;

  int cur = 0;
  for (int ch = cBeg; ch < cEnd; ++ch) {
    // ---- 1: ms loads first (so their waitcnt doesn't drain the prefetch), then async stage ch+1
    const float4 msA = *(const float4*)(msb + (size_t)ch * NC);
    const float4 msB = *(const float4*)(msb + (size_t)ch * NC + 16);
    __builtin_amdgcn_sched_barrier(0);
    if (ch + 1 < cEnd) {
      size_t omv = (size_t)(ch + 1) * (NC * 2);
      size_t omk = (size_t)(ch + 1) * (NC * CKP * 2);
      char* dv = (char*)MVs[cur ^ 1];
      char* dk = (char*)MKs[cur ^ 1];
      #pragma unroll
      for (int k = 0; k < 4; ++k) gload_lds16(mvb[k] + omv, dv + dmv[k]);
      #pragma unroll
      for (int k = 0; k < 2; ++k) gload_lds16(mkb[k] + omk, dk + dmk[k]);
    }

    // ---- 2: S GEMM: 64n x 128q, K=128
    const _Float16* MKc = MKs[cur];
    f32x4 sacc[2][2];
    #pragma unroll
    for (int i = 0; i < 2; ++i)
      #pragma unroll
      for (int j = 0; j < 2; ++j) sacc[i][j] = (f32x4)0.f;
    #pragma unroll
    for (int ks = 0; ks < 4; ++ks) {
      f16x8 af[2], bf[2];
      #pragma unroll
      for (int i = 0; i < 2; ++i) {
        int n_loc = nh * 32 + i * 16 + l15;
        af[i] = *((const f16x8*)(&MKc[n_loc * CKP + (((ks * 4 + g) ^ (n_loc & 7)) * 8)]));
      }
      #pragma unroll
      for (int j = 0; j < 2; ++j) {
        int q_loc = qw * 32 + j * 16 + l15;
        bf[j] = *((const f16x8*)(&Qs[q_loc * CKP + (((ks * 4 + g) ^ (q_loc & 7)) * 8)]));
      }
      #pragma unroll
      for (int i = 0; i < 2; ++i)
        #pragma unroll
        for (int j = 0; j < 2; ++j)
          sacc[i][j] = __builtin_amdgcn_mfma_f32_16x16x32_f16(af[i], bf[j], sacc[i][j], 0, 0, 0);
    }

    // ---- 3: p = exp2((S - bsq)*ms*log2e/8); Ps fp16 (swizzled); l partials
    const float K = 0.125f * 1.44269504f;
    #pragma unroll
    for (int i = 0; i < 2; ++i) {
      int nbase = nh * 32 + i * 16 + g * 4;
      float m0 = (i ? msB.x : msA.x) * K;
      float m1 = (i ? msB.y : msA.y) * K;
      float m2 = (i ? msB.z : msA.z) * K;
      float m3 = (i ? msB.w : msA.w) * K;
      #pragma unroll
      for (int j = 0; j < 2; ++j) {
        int q_loc = qw * 32 + j * 16 + l15;
        float bqv = bsqs[q_loc];
        float p0 = exp2f((sacc[i][j][0] - bqv) * m0);
        float p1 = exp2f((sacc[i][j][1] - bqv) * m1);
        float p2 = exp2f((sacc[i][j][2] - bqv) * m2);
        float p3 = exp2f((sacc[i][j][3] - bqv) * m3);
        float psum = (p0 + p1) + (p2 + p3);
        if (j == 0) lp0 += psum; else lp1 += psum;
        f16x4 ph;
        ph[0]=(_Float16)p0; ph[1]=(_Float16)p1; ph[2]=(_Float16)p2; ph[3]=(_Float16)p3;
        int nb = nbase >> 3;
        int off4 = nbase & 7;
        *((f16x4*)(&Ps[q_loc * NC + ((nb ^ (q_loc & 7)) * 8) + off4])) = ph;
      }
    }

    // ---- 4: Ps visible to all waves (LDS only; do NOT drain vmcnt)
    asm volatile("s_waitcnt lgkmcnt(0)" ::: "memory");
    __builtin_amdgcn_s_barrier();
    __builtin_amdgcn_sched_barrier(0);

    // ---- 5: readout GEMM: 256v x 128q, K=64
    const _Float16* MVc = MVs[cur];
    #pragma unroll
    for (int ks = 0; ks < 2; ++ks) {
      f16x8 av[4], bp[4];
      #pragma unroll
      for (int i = 0; i < 4; ++i) {
        int v_loc = wv * 64 + i * 16 + l15;
        av[i] = *((const f16x8*)(&MVc[v_loc * NC + (((ks * 4 + g) ^ (v_loc & 7)) * 8)]));
      }
      #pragma unroll
      for (int j = 0; j < 4; ++j) {
        int q_loc = wq * 64 + j * 16 + l15;
        bp[j] = *((const f16x8*)(&Ps[q_loc * NC + (((ks * 4 + g) ^ (q_loc & 7)) * 8)]));
      }
      #pragma unroll
      for (int i = 0; i < 4; ++i)
        #pragma unroll
        for (int j = 0; j < 4; ++j)
          acc[i][j] = __builtin_amdgcn_mfma_f32_16x16x32_f16(av[i], bp[j], acc[i][j], 0, 0, 0);
    }

    // ---- 6: next-chunk staging landed; everyone done reading cur & Ps
    asm volatile("s_waitcnt vmcnt(0)" ::: "memory");
    __builtin_amdgcn_s_barrier();
    __builtin_amdgcn_sched_barrier(0);
    cur ^= 1;
  }

  // epilogue: reduce per-lane l partials (8 contributors per q)
  {
    int q0a = qw * 32 + l15;
    lred[q0a * 8 + nh * 4 + g] = lp0;
    lred[(q0a + 16) * 8 + nh * 4 + g] = lp1;
  }
  __syncthreads();
  if (tid < QT) {
    float s = 0.f;
    #pragma unroll
    for (int j = 0; j < 8; ++j) s += lred[tid * 8 + j];
    lpart[((size_t)b * NSPLIT + nsp) * HWP + qt * QT + tid] = s;
  }
  #pragma unroll
  for (int i = 0; i < 4; ++i) {
    #pragma unroll
    for (int j = 0; j < 4; ++j) {
      #pragma unroll
      for (int r = 0; r < 4; ++r) {
        int v_glob = vt * VT + wv * 64 + i * 16 + g * 4 + r;
        int q_l = qt * QT + wq * 64 + j * 16 + l15;
        pO[(((size_t)b * NSPLIT + nsp) * OCV + v_glob) * HWP + q_l] = acc[i][j][r];
      }
    }
  }
}

// ---- final: out = (O'0 + O'1) / (l0 + l1)
__global__ void k_reduce(const float* __restrict__ pO, const float* __restrict__ lpart,
                         float* __restrict__ out) {
  int i = blockIdx.x * 256 + threadIdx.x;
  int q4 = i % 405;
  int rest = i / 405;
  int v = rest & (OCV - 1);
  int b = rest >> 10;
  int q = q4 * 4;
  const float4 p0 = *((const float4*)(pO + (((size_t)b * NSPLIT + 0) * OCV + v) * HWP + q));
  const float4 p1 = *((const float4*)(pO + (((size_t)b * NSPLIT + 1) * OCV + v) * HWP + q));
  const float4 l0 = *((const float4*)(lpart + ((size_t)b * NSPLIT + 0) * HWP + q));
  const float4 l1 = *((const float4*)(lpart + ((size_t)b * NSPLIT + 1) * HWP + q));
  float4 o;
  o.x = (p0.x + p1.x) / (l0.x + l1.x);
  o.y = (p0.y + p1.y) / (l0.y + l1.y);
  o.z = (p0.z + p1.z) / (l0.z + l1.z);
  o.w = (p0.w + p1.w) / (l0.w + l1.w);
  *((float4*)(out + ((size_t)b * OCV + v) * HW + q)) = o;
}

extern "C" void kernel_launch(void* const* d_in, const int* in_sizes, int n_in,
                              void* d_out, int out_size, void* d_ws, size_t ws_size,
                              hipStream_t stream) {
  const float* qk = (const float*)d_in[0];
  const float* qe = (const float*)d_in[1];
  const float* mk = (const float*)d_in[2];
  const float* ms = (const float*)d_in[3];
  const float* mv = (const float*)d_in[4];
  float* out = (float*)d_out;

  char* p = (char*)d_ws;
  _Float16* mvh = (_Float16*)p; p += (size_t)2 * OCV * NTOT * 2;
  _Float16* mkp = (_Float16*)p; p += (size_t)2 * NTOT * CKP * 2;
  _Float16* qp  = (_Float16*)p; p += (size_t)2 * HWP * CKP * 2;
  float* bsqw   = (float*)p;    p += (size_t)2 * HWP * 4;
  float* lpart  = (float*)p;    p += (size_t)2 * NSPLIT * HWP * 4;
  float* pO     = (float*)p;    p += (size_t)2 * NSPLIT * OCV * HWP * 4;
  size_t need = (size_t)(p - (char*)d_ws);
  if (ws_size < need) return;

  k_prep_mv<<<25920, 256, 0, stream>>>(mv, mvh);
  k_prep_mk<<<dim3(405, 2), 256, 0, stream>>>(mk, mkp);
  k_prep_q<<<dim3(NQT, 2), QT, 0, stream>>>(qk, qe, qp, bsqw);
  k_main<<<dim3(NQT, NVT, 4), 512, 0, stream>>>(mvh, mkp, qp, bsqw, ms, pO, lpart);
  k_reduce<<<3240, 256, 0, stream>>>(pO, lpart, out);
}